// Round 14
// baseline (171.761 us; speedup 1.0000x reference)
//
#include <hip/hip_runtime.h>
#include <math.h>

// GCN 2-layer, algebraically fused:
//   agg_x[d] = dinv[d]*(sum_{s in N(d)} xp[s] + xp[d]),  xp = dinv*x
//   h = relu(agg_x@W1+b1); g = h@W2; gp = dinv*g
//   out = log_softmax(dinv[d]*(sum gp[s] + gp[d]) + b2)
//
// R10: two-level counting sort -> node-contiguous records; segmented sums.
// R11 (157.8us, BEST): uint4 record loads, MLP fused into agg1.
// R12 (regressed): scatter occupancy + 8-lane gathers -> reverted.
// R13: bsort split into k_deg (hist -> dinv/xp/nodeoff) + k_bsort2 (cursors
//      free from nodeoff — no scan; scatter to nsorted + gather xp + SoA LDS
//      accumulate + fused MLP -> gp). Kills k_agg1's entire record pass
//      (12.8MB read + 3.2M gather issues now piggyback on bsort2's
//      latency-bound loop). Cross-bucket xp dependency satisfied by the
//      k_deg kernel boundary.

#define BLK 256
#define NTILE 512
#define EPTMAX 6400        // >= runtime ept (6252), multiple of 4
#define MAXB 512           // >= nbkt = 391

// ---------- Phase A (R11 config) ----------

__global__ void k_hist(const int* __restrict__ dst, int* __restrict__ table,
                       int e, int ept, int nbkt) {
    __shared__ int h[MAXB];
    int tile = blockIdx.x;
    for (int i = threadIdx.x; i < MAXB; i += BLK) h[i] = 0;
    __syncthreads();
    int lo = tile * ept;
    int hi = min(lo + ept, e);
    for (int i = lo + 4 * threadIdx.x; i < hi; i += 4 * BLK) {
        int4 d4 = *(const int4*)(dst + i);
        atomicAdd(&h[d4.x >> 8], 1);
        atomicAdd(&h[d4.y >> 8], 1);
        atomicAdd(&h[d4.z >> 8], 1);
        atomicAdd(&h[d4.w >> 8], 1);
    }
    __syncthreads();
    for (int i = threadIdx.x; i < nbkt; i += BLK)
        table[tile * nbkt + i] = h[i];
}

__global__ __launch_bounds__(NTILE) void k_scan_col(
        int* __restrict__ table, int* __restrict__ tot, int nbkt) {
    __shared__ int wsum[NTILE / 64];
    int b = blockIdx.x;
    int t = threadIdx.x;
    int v = table[t * nbkt + b];
    int x = v;
    int lane = t & 63;
#pragma unroll
    for (int ofs = 1; ofs < 64; ofs <<= 1) {
        int y = __shfl_up(x, ofs, 64);
        if (lane >= ofs) x += y;
    }
    if (lane == 63) wsum[t >> 6] = x;
    __syncthreads();
    if (t < NTILE / 64) {
        int s = wsum[t];
        int w = s;
#pragma unroll
        for (int ofs = 1; ofs < NTILE / 64; ofs <<= 1) {
            int y = __shfl_up(w, ofs, 64);
            if (t >= ofs) w += y;
        }
        wsum[t] = w - s;
    }
    __syncthreads();
    int incl = x + wsum[t >> 6];
    table[t * nbkt + b] = incl - v;
    if (t == NTILE - 1) tot[b] = incl;
}

__global__ void k_scan_tot(const int* __restrict__ tot, int* __restrict__ bkt_off, int nbkt) {
    __shared__ int wsum[MAXB / 64];
    int t = threadIdx.x;               // MAXB threads
    int v = (t < nbkt) ? tot[t] : 0;
    int x = v;
    int lane = t & 63;
#pragma unroll
    for (int ofs = 1; ofs < 64; ofs <<= 1) {
        int y = __shfl_up(x, ofs, 64);
        if (lane >= ofs) x += y;
    }
    if (lane == 63) wsum[t >> 6] = x;
    __syncthreads();
    if (t < MAXB / 64) {
        int s = wsum[t];
        int w = s;
#pragma unroll
        for (int ofs = 1; ofs < MAXB / 64; ofs <<= 1) {
            int y = __shfl_up(w, ofs, 64);
            if (t >= ofs) w += y;
        }
        wsum[t] = w - s;
    }
    __syncthreads();
    int incl = x + wsum[t >> 6];
    if (t < nbkt) bkt_off[t] = incl - v;
    if (t == nbkt - 1) bkt_off[nbkt] = incl;
}

__global__ void k_scatter(const int* __restrict__ src, const int* __restrict__ dst,
                          const int* __restrict__ table, const int* __restrict__ tot,
                          const int* __restrict__ bkt_off, unsigned* __restrict__ sorted,
                          int e, int ept, int nbkt) {
    __shared__ int cur[MAXB];
    __shared__ int base2[MAXB];
    __shared__ unsigned stage[EPTMAX];
    __shared__ unsigned short stage_b[EPTMAX];
    __shared__ int wpart[BLK / 64];
    int tile = blockIdx.x;
    int t = threadIdx.x;
    int lo = tile * ept;
    int hi = min(lo + ept, e);
    int total = hi - lo;

    int b0 = 2 * t, b1 = 2 * t + 1;
    int c0 = 0, c1 = 0, g0 = 0, g1 = 0;
    if (b0 < nbkt) {
        int base = table[tile * nbkt + b0];
        int next = (tile < NTILE - 1) ? table[(tile + 1) * nbkt + b0] : tot[b0];
        c0 = next - base;
        g0 = bkt_off[b0] + base;
    }
    if (b1 < nbkt) {
        int base = table[tile * nbkt + b1];
        int next = (tile < NTILE - 1) ? table[(tile + 1) * nbkt + b1] : tot[b1];
        c1 = next - base;
        g1 = bkt_off[b1] + base;
    }
    int p = c0 + c1;
    int x = p;
    int lane = t & 63;
#pragma unroll
    for (int ofs = 1; ofs < 64; ofs <<= 1) {
        int y = __shfl_up(x, ofs, 64);
        if (lane >= ofs) x += y;
    }
    if (lane == 63) wpart[t >> 6] = x;
    __syncthreads();
    if (t < BLK / 64) {
        int s = wpart[t];
        int w = s;
#pragma unroll
        for (int ofs = 1; ofs < BLK / 64; ofs <<= 1) {
            int y = __shfl_up(w, ofs, 64);
            if (t >= ofs) w += y;
        }
        wpart[t] = w - s;
    }
    __syncthreads();
    int E = x + wpart[t >> 6] - p;
    cur[b0] = E;
    cur[b1] = E + c0;
    if (b0 < nbkt) base2[b0] = g0 - E;
    if (b1 < nbkt) base2[b1] = g1 - (E + c0);
    __syncthreads();

    for (int i = lo + 4 * t; i < hi; i += 4 * BLK) {
        int4 s4 = *(const int4*)(src + i);
        int4 d4 = *(const int4*)(dst + i);
        int b, pos;
        b = d4.x >> 8; pos = atomicAdd(&cur[b], 1);
        stage[pos] = (unsigned)s4.x | ((unsigned)(d4.x & 255) << 17); stage_b[pos] = (unsigned short)b;
        b = d4.y >> 8; pos = atomicAdd(&cur[b], 1);
        stage[pos] = (unsigned)s4.y | ((unsigned)(d4.y & 255) << 17); stage_b[pos] = (unsigned short)b;
        b = d4.z >> 8; pos = atomicAdd(&cur[b], 1);
        stage[pos] = (unsigned)s4.z | ((unsigned)(d4.z & 255) << 17); stage_b[pos] = (unsigned short)b;
        b = d4.w >> 8; pos = atomicAdd(&cur[b], 1);
        stage[pos] = (unsigned)s4.w | ((unsigned)(d4.w & 255) << 17); stage_b[pos] = (unsigned short)b;
    }
    __syncthreads();
    for (int j = t; j < total; j += BLK) {
        int b = stage_b[j];
        sorted[base2[b] + j] = stage[j];
    }
}

// ---------- k_deg: per-bucket histogram -> dinv, xp, nodeoff ----------
__global__ __launch_bounds__(1024) void k_deg(
        const unsigned* __restrict__ sorted, const int* __restrict__ bkt_off,
        const float* __restrict__ x, float* __restrict__ dinv,
        float* __restrict__ xp, int* __restrict__ nodeoff, int n) {
    __shared__ int cnt[256];
    __shared__ int wsum[16];
    int b = blockIdx.x, t = threadIdx.x;
    if (t < 256) cnt[t] = 0;
    __syncthreads();
    int lo = bkt_off[b], hi = bkt_off[b + 1];
    int la = lo & ~3;
    for (int i = la + 4 * t; i < hi; i += 4 * 1024) {
        uint4 r = *(const uint4*)(sorted + i);   // aligned; pad covers overread
        if (i >= lo && i + 4 <= hi) {
            atomicAdd(&cnt[r.x >> 17], 1);
            atomicAdd(&cnt[r.y >> 17], 1);
            atomicAdd(&cnt[r.z >> 17], 1);
            atomicAdd(&cnt[r.w >> 17], 1);
        } else {
            if (i + 0 >= lo && i + 0 < hi) atomicAdd(&cnt[r.x >> 17], 1);
            if (i + 1 >= lo && i + 1 < hi) atomicAdd(&cnt[r.y >> 17], 1);
            if (i + 2 >= lo && i + 2 < hi) atomicAdd(&cnt[r.z >> 17], 1);
            if (i + 3 >= lo && i + 3 < hi) atomicAdd(&cnt[r.w >> 17], 1);
        }
    }
    __syncthreads();
    int c = (t < 256) ? cnt[t] : 0;
    int node = (b << 8) + t;
    if (t < 256 && node < n) {
        float d = rsqrtf((float)c + 1.0f);   // +1 self loop
        dinv[node] = d;
        float2 xv = ((const float2*)x)[node];
        ((float2*)xp)[node] = make_float2(d * xv.x, d * xv.y);
    }
    // exclusive scan of cnt -> absolute node offsets
    int xsc = c;
    int lane = t & 63;
#pragma unroll
    for (int ofs = 1; ofs < 64; ofs <<= 1) {
        int y = __shfl_up(xsc, ofs, 64);
        if (lane >= ofs) xsc += y;
    }
    if (lane == 63) wsum[t >> 6] = xsc;
    __syncthreads();
    if (t < 4) {
        int s = wsum[t];
        int w = s;
#pragma unroll
        for (int ofs = 1; ofs < 4; ofs <<= 1) {
            int y = __shfl_up(w, ofs, 64);
            if (t >= ofs) w += y;
        }
        wsum[t] = w - s;
    }
    __syncthreads();
    if (t < 256)
        nodeoff[(b << 8) + t] = lo + xsc + wsum[t >> 6] - c;
}

// ---------- k_bsort2: node-scatter + xp-gather-accumulate + fused MLP ----------
// cursors come free from nodeoff (no scan). Writes nsorted (for agg2) AND
// gp[node] = dinv*(relu((dinv*(sum xp + self))@W1+b1)@W2).
__global__ __launch_bounds__(1024) void k_bsort2(
        const unsigned* __restrict__ sorted, const int* __restrict__ bkt_off,
        const int* __restrict__ nodeoff, const float* __restrict__ xp,
        const float* __restrict__ dinv,
        const float* __restrict__ W1, const float* __restrict__ b1,
        const float* __restrict__ W2,
        unsigned* __restrict__ nsorted, float* __restrict__ gp, int n) {
    __shared__ int cur[256];
    __shared__ float accx[256];
    __shared__ float accy[256];
    int b = blockIdx.x, t = threadIdx.x;
    if (t < 256) {
        cur[t] = nodeoff[(b << 8) + t];   // absolute positions
        accx[t] = 0.f;
        accy[t] = 0.f;
    }
    __syncthreads();
    int lo = bkt_off[b], hi = bkt_off[b + 1];
    int la = lo & ~3;
    const float2* xp2 = (const float2*)xp;
    for (int i = la + 4 * t; i < hi; i += 4 * 1024) {
        uint4 r = *(const uint4*)(sorted + i);
        if (i >= lo && i + 4 <= hi) {
            int s0 = r.x & 0x1FFFFu, d0 = r.x >> 17;
            int s1 = r.y & 0x1FFFFu, d1 = r.y >> 17;
            int s2 = r.z & 0x1FFFFu, d2 = r.z >> 17;
            int s3 = r.w & 0x1FFFFu, d3 = r.w >> 17;
            float2 f0 = xp2[s0], f1 = xp2[s1], f2 = xp2[s2], f3 = xp2[s3];
            int p0 = atomicAdd(&cur[d0], 1); nsorted[p0] = (unsigned)s0;
            int p1 = atomicAdd(&cur[d1], 1); nsorted[p1] = (unsigned)s1;
            int p2 = atomicAdd(&cur[d2], 1); nsorted[p2] = (unsigned)s2;
            int p3 = atomicAdd(&cur[d3], 1); nsorted[p3] = (unsigned)s3;
            atomicAdd(&accx[d0], f0.x); atomicAdd(&accy[d0], f0.y);
            atomicAdd(&accx[d1], f1.x); atomicAdd(&accy[d1], f1.y);
            atomicAdd(&accx[d2], f2.x); atomicAdd(&accy[d2], f2.y);
            atomicAdd(&accx[d3], f3.x); atomicAdd(&accy[d3], f3.y);
        } else {
            unsigned rr[4] = {r.x, r.y, r.z, r.w};
            for (int k = 0; k < 4; ++k) {
                if (i + k >= lo && i + k < hi) {
                    int s = rr[k] & 0x1FFFFu, d = rr[k] >> 17;
                    float2 f = xp2[s];
                    int p = atomicAdd(&cur[d], 1); nsorted[p] = (unsigned)s;
                    atomicAdd(&accx[d], f.x); atomicAdd(&accy[d], f.y);
                }
            }
        }
    }
    __syncthreads();
    int node = (b << 8) + t;
    if (t < 256 && node < n) {
        float d = dinv[node];
        float2 xv = xp2[node];
        float ax = d * (accx[t] + xv.x), ay = d * (accy[t] + xv.y);
        float g0 = 0.f, g1 = 0.f;
#pragma unroll
        for (int f = 0; f < 16; ++f) {
            float h = fmaf(ax, W1[f], fmaf(ay, W1[16 + f], b1[f]));
            h = fmaxf(h, 0.0f);
            g0 = fmaf(h, W2[2 * f + 0], g0);
            g1 = fmaf(h, W2[2 * f + 1], g1);
        }
        ((float2*)gp)[node] = make_float2(d * g0, d * g1);
    }
}

// ---------- agg2: segmented sum + bias + log_softmax (R11 form) ----------
__global__ void k_agg2(const unsigned* __restrict__ nsorted, const int* __restrict__ nodeoff,
                       const float* __restrict__ gp, const float* __restrict__ dinv,
                       const float* __restrict__ b2, float* __restrict__ out, int n) {
    int t = threadIdx.x;
    int nd = (blockIdx.x << 8) + (blockIdx.y << 6) + (t >> 2);
    int q = t & 3;
    if (nd >= n) return;
    int start = nodeoff[nd], end = nodeoff[nd + 1];
    const float2* gp2 = (const float2*)gp;
    float sx = 0.f, sy = 0.f;
    for (int p = (start & ~3) + 4 * q; p < end; p += 16) {
        uint4 r = *(const uint4*)(nsorted + p);
        if (p >= start && p + 4 <= end) {
            float2 f0 = gp2[r.x], f1 = gp2[r.y], f2 = gp2[r.z], f3 = gp2[r.w];
            sx += (f0.x + f1.x) + (f2.x + f3.x);
            sy += (f0.y + f1.y) + (f2.y + f3.y);
        } else {
            if (p + 0 >= start && p + 0 < end) { float2 f = gp2[r.x]; sx += f.x; sy += f.y; }
            if (p + 1 >= start && p + 1 < end) { float2 f = gp2[r.y]; sx += f.x; sy += f.y; }
            if (p + 2 >= start && p + 2 < end) { float2 f = gp2[r.z]; sx += f.x; sy += f.y; }
            if (p + 3 >= start && p + 3 < end) { float2 f = gp2[r.w]; sx += f.x; sy += f.y; }
        }
    }
    sx += __shfl_xor(sx, 1); sy += __shfl_xor(sy, 1);
    sx += __shfl_xor(sx, 2); sy += __shfl_xor(sy, 2);
    if (q == 0) {
        float d = dinv[nd];
        float2 gv = gp2[nd];
        float z0 = d * (sx + gv.x) + b2[0];
        float z1 = d * (sy + gv.y) + b2[1];
        float m = fmaxf(z0, z1);
        float lse = m + logf(expf(z0 - m) + expf(z1 - m));
        ((float2*)out)[nd] = make_float2(z0 - lse, z1 - lse);
    }
}

extern "C" void kernel_launch(void* const* d_in, const int* in_sizes, int n_in,
                              void* d_out, int out_size, void* d_ws, size_t ws_size,
                              hipStream_t stream) {
    const float* x  = (const float*)d_in[0];   // [n,2]
    const int*   ei = (const int*)d_in[1];     // [2,e]: row0=src, row1=dst
    const float* W1 = (const float*)d_in[2];   // [2,16]
    const float* b1 = (const float*)d_in[3];   // [16]
    const float* W2 = (const float*)d_in[4];   // [16,2]
    const float* b2 = (const float*)d_in[5];   // [2]
    float* out = (float*)d_out;                // [n,2]

    const int n = in_sizes[0] / 2;             // 100000
    const int e = in_sizes[1] / 2;             // 3200000
    const int* src = ei;
    const int* dst = ei + e;

    const int nbkt = (n + 255) >> 8;           // 391
    int ept = (((e + NTILE - 1) / NTILE) + 3) & ~3;   // 6252

    char* base = (char*)d_ws;
    size_t off = 0;
    auto take = [&](size_t bytes) { char* p = base + off; off += (bytes + 255) & ~(size_t)255; return p; };
    unsigned* sorted  = (unsigned*)take(((size_t)e + 8) * 4);             // 12.8 MB (+pad)
    int*      table   = (int*)take((size_t)NTILE * nbkt * 4);             // 0.8 MB
    int*      tot     = (int*)take((size_t)MAXB * 4);
    int*      bkt_off = (int*)take((size_t)(MAXB + 1) * 4);
    unsigned* nsorted = (unsigned*)take(((size_t)e + 8) * 4);             // 12.8 MB (+pad)
    int*      nodeoff = (int*)take((size_t)(nbkt * 256 + 64) * 4);        // 0.4 MB
    float*    dinv    = (float*)take((size_t)n * 4);
    float*    xp      = (float*)take((size_t)n * 8);
    float*    gp      = (float*)take((size_t)n * 8);

    dim3 gagg(nbkt, 4);

    k_hist    <<<NTILE, BLK, 0, stream>>>(dst, table, e, ept, nbkt);
    k_scan_col<<<nbkt, NTILE, 0, stream>>>(table, tot, nbkt);
    k_scan_tot<<<1, MAXB, 0, stream>>>(tot, bkt_off, nbkt);
    k_scatter <<<NTILE, BLK, 0, stream>>>(src, dst, table, tot, bkt_off, sorted, e, ept, nbkt);
    k_deg     <<<nbkt, 1024, 0, stream>>>(sorted, bkt_off, x, dinv, xp, nodeoff, n);
    k_bsort2  <<<nbkt, 1024, 0, stream>>>(sorted, bkt_off, nodeoff, xp, dinv, W1, b1, W2, nsorted, gp, n);
    k_agg2    <<<gagg, BLK, 0, stream>>>(nsorted, nodeoff, gp, dinv, b2, out, n);
}

// Round 15
// 158.426 us; speedup vs baseline: 1.0842x; 1.0842x over previous
//
#include <hip/hip_runtime.h>
#include <math.h>

// GCN 2-layer, algebraically fused — FINAL (R11 config, measured best 157.8us):
//   agg_x[d] = dinv[d]*(sum_{s in N(d)} xp[s] + xp[d]),  xp = dinv*x
//   h = relu(agg_x@W1+b1); g = h@W2; gp = dinv*g
//   out = log_softmax(dinv[d]*(sum gp[s] + gp[d]) + b2)
//
// Pipeline: tile-hist -> parallel scans -> staged counting-sort scatter
// (bucket = dst>>8) -> per-bucket node-sort (degree/dinv/xp fall out free)
// -> atomic-free segmented-sum aggregation (4 lanes/node, shfl_xor reduce),
// MLP fused into agg1 epilogue, bias+log_softmax fused into agg2.
// R12 (occupancy/8-lane gathers) and R13 (bsort2 fusion) both regressed and
// are reverted. Residual: ~45us fixed harness ws-poison fill + latency-bound
// irregular gathers (~200cyc L2, request-rate bound, not BW bound).

#define BLK 256
#define NTILE 512
#define EPTMAX 6400        // >= runtime ept (6252), multiple of 4
#define MAXB 512           // >= nbkt = 391

// ---------- Phase A ----------

__global__ void k_hist(const int* __restrict__ dst, int* __restrict__ table,
                       int e, int ept, int nbkt) {
    __shared__ int h[MAXB];
    int tile = blockIdx.x;
    for (int i = threadIdx.x; i < MAXB; i += BLK) h[i] = 0;
    __syncthreads();
    int lo = tile * ept;
    int hi = min(lo + ept, e);
    for (int i = lo + 4 * threadIdx.x; i < hi; i += 4 * BLK) {
        int4 d4 = *(const int4*)(dst + i);
        atomicAdd(&h[d4.x >> 8], 1);
        atomicAdd(&h[d4.y >> 8], 1);
        atomicAdd(&h[d4.z >> 8], 1);
        atomicAdd(&h[d4.w >> 8], 1);
    }
    __syncthreads();
    for (int i = threadIdx.x; i < nbkt; i += BLK)
        table[tile * nbkt + i] = h[i];
}

__global__ void k_scan_col(int* __restrict__ table, int* __restrict__ tot, int nbkt) {
    __shared__ int wsum[NTILE / 64];
    int b = blockIdx.x;
    int t = threadIdx.x;
    int v = table[t * nbkt + b];
    int x = v;
    int lane = t & 63;
#pragma unroll
    for (int ofs = 1; ofs < 64; ofs <<= 1) {
        int y = __shfl_up(x, ofs, 64);
        if (lane >= ofs) x += y;
    }
    if (lane == 63) wsum[t >> 6] = x;
    __syncthreads();
    if (t < NTILE / 64) {
        int s = wsum[t];
        int w = s;
#pragma unroll
        for (int ofs = 1; ofs < NTILE / 64; ofs <<= 1) {
            int y = __shfl_up(w, ofs, 64);
            if (t >= ofs) w += y;
        }
        wsum[t] = w - s;
    }
    __syncthreads();
    int incl = x + wsum[t >> 6];
    table[t * nbkt + b] = incl - v;
    if (t == NTILE - 1) tot[b] = incl;
}

__global__ void k_scan_tot(const int* __restrict__ tot, int* __restrict__ bkt_off, int nbkt) {
    __shared__ int wsum[MAXB / 64];
    int t = threadIdx.x;               // MAXB threads
    int v = (t < nbkt) ? tot[t] : 0;
    int x = v;
    int lane = t & 63;
#pragma unroll
    for (int ofs = 1; ofs < 64; ofs <<= 1) {
        int y = __shfl_up(x, ofs, 64);
        if (lane >= ofs) x += y;
    }
    if (lane == 63) wsum[t >> 6] = x;
    __syncthreads();
    if (t < MAXB / 64) {
        int s = wsum[t];
        int w = s;
#pragma unroll
        for (int ofs = 1; ofs < MAXB / 64; ofs <<= 1) {
            int y = __shfl_up(w, ofs, 64);
            if (t >= ofs) w += y;
        }
        wsum[t] = w - s;
    }
    __syncthreads();
    int incl = x + wsum[t >> 6];
    if (t < nbkt) bkt_off[t] = incl - v;
    if (t == nbkt - 1) bkt_off[nbkt] = incl;
}

__global__ void k_scatter(const int* __restrict__ src, const int* __restrict__ dst,
                          const int* __restrict__ table, const int* __restrict__ tot,
                          const int* __restrict__ bkt_off, unsigned* __restrict__ sorted,
                          int e, int ept, int nbkt) {
    __shared__ int cur[MAXB];
    __shared__ int base2[MAXB];
    __shared__ unsigned stage[EPTMAX];
    __shared__ unsigned short stage_b[EPTMAX];
    __shared__ int wpart[BLK / 64];
    int tile = blockIdx.x;
    int t = threadIdx.x;
    int lo = tile * ept;
    int hi = min(lo + ept, e);
    int total = hi - lo;

    int b0 = 2 * t, b1 = 2 * t + 1;
    int c0 = 0, c1 = 0, g0 = 0, g1 = 0;
    if (b0 < nbkt) {
        int base = table[tile * nbkt + b0];
        int next = (tile < NTILE - 1) ? table[(tile + 1) * nbkt + b0] : tot[b0];
        c0 = next - base;
        g0 = bkt_off[b0] + base;
    }
    if (b1 < nbkt) {
        int base = table[tile * nbkt + b1];
        int next = (tile < NTILE - 1) ? table[(tile + 1) * nbkt + b1] : tot[b1];
        c1 = next - base;
        g1 = bkt_off[b1] + base;
    }
    int p = c0 + c1;
    int x = p;
    int lane = t & 63;
#pragma unroll
    for (int ofs = 1; ofs < 64; ofs <<= 1) {
        int y = __shfl_up(x, ofs, 64);
        if (lane >= ofs) x += y;
    }
    if (lane == 63) wpart[t >> 6] = x;
    __syncthreads();
    if (t < BLK / 64) {
        int s = wpart[t];
        int w = s;
#pragma unroll
        for (int ofs = 1; ofs < BLK / 64; ofs <<= 1) {
            int y = __shfl_up(w, ofs, 64);
            if (t >= ofs) w += y;
        }
        wpart[t] = w - s;
    }
    __syncthreads();
    int E = x + wpart[t >> 6] - p;
    cur[b0] = E;
    cur[b1] = E + c0;
    if (b0 < nbkt) base2[b0] = g0 - E;
    if (b1 < nbkt) base2[b1] = g1 - (E + c0);
    __syncthreads();

    for (int i = lo + 4 * t; i < hi; i += 4 * BLK) {
        int4 s4 = *(const int4*)(src + i);
        int4 d4 = *(const int4*)(dst + i);
        int b, pos;
        b = d4.x >> 8; pos = atomicAdd(&cur[b], 1);
        stage[pos] = (unsigned)s4.x | ((unsigned)(d4.x & 255) << 17); stage_b[pos] = (unsigned short)b;
        b = d4.y >> 8; pos = atomicAdd(&cur[b], 1);
        stage[pos] = (unsigned)s4.y | ((unsigned)(d4.y & 255) << 17); stage_b[pos] = (unsigned short)b;
        b = d4.z >> 8; pos = atomicAdd(&cur[b], 1);
        stage[pos] = (unsigned)s4.z | ((unsigned)(d4.z & 255) << 17); stage_b[pos] = (unsigned short)b;
        b = d4.w >> 8; pos = atomicAdd(&cur[b], 1);
        stage[pos] = (unsigned)s4.w | ((unsigned)(d4.w & 255) << 17); stage_b[pos] = (unsigned short)b;
    }
    __syncthreads();
    for (int j = t; j < total; j += BLK) {
        int b = stage_b[j];
        sorted[base2[b] + j] = stage[j];
    }
}

// ---------- per-bucket node-sort + degree + dinv + xp (uint4 passes) ----------
__global__ __launch_bounds__(1024) void k_bsort(
        const unsigned* __restrict__ sorted, const int* __restrict__ bkt_off,
        const float* __restrict__ x, float* __restrict__ dinv,
        float* __restrict__ xp, unsigned* __restrict__ nsorted,
        int* __restrict__ nodeoff, int n) {
    __shared__ int cnt[256];
    __shared__ int cur[256];
    __shared__ int wsum[16];
    int b = blockIdx.x, t = threadIdx.x;
    if (t < 256) cnt[t] = 0;
    __syncthreads();
    int lo = bkt_off[b], hi = bkt_off[b + 1];
    int la = lo & ~3;
    for (int i = la + 4 * t; i < hi; i += 4 * 1024) {
        uint4 r = *(const uint4*)(sorted + i);   // aligned; pad covers overread
        if (i >= lo && i + 4 <= hi) {
            atomicAdd(&cnt[r.x >> 17], 1);
            atomicAdd(&cnt[r.y >> 17], 1);
            atomicAdd(&cnt[r.z >> 17], 1);
            atomicAdd(&cnt[r.w >> 17], 1);
        } else {
            if (i + 0 >= lo && i + 0 < hi) atomicAdd(&cnt[r.x >> 17], 1);
            if (i + 1 >= lo && i + 1 < hi) atomicAdd(&cnt[r.y >> 17], 1);
            if (i + 2 >= lo && i + 2 < hi) atomicAdd(&cnt[r.z >> 17], 1);
            if (i + 3 >= lo && i + 3 < hi) atomicAdd(&cnt[r.w >> 17], 1);
        }
    }
    __syncthreads();
    int c = (t < 256) ? cnt[t] : 0;
    int node = (b << 8) + t;
    if (t < 256 && node < n) {
        float d = rsqrtf((float)c + 1.0f);   // +1 self loop
        dinv[node] = d;
        float2 xv = ((const float2*)x)[node];
        ((float2*)xp)[node] = make_float2(d * xv.x, d * xv.y);
    }
    int xsc = c;
    int lane = t & 63;
#pragma unroll
    for (int ofs = 1; ofs < 64; ofs <<= 1) {
        int y = __shfl_up(xsc, ofs, 64);
        if (lane >= ofs) xsc += y;
    }
    if (lane == 63) wsum[t >> 6] = xsc;
    __syncthreads();
    if (t < 4) {
        int s = wsum[t];
        int w = s;
#pragma unroll
        for (int ofs = 1; ofs < 4; ofs <<= 1) {
            int y = __shfl_up(w, ofs, 64);
            if (t >= ofs) w += y;
        }
        wsum[t] = w - s;
    }
    __syncthreads();
    if (t < 256) {
        int excl = xsc + wsum[t >> 6] - c;
        cur[t] = excl;
        nodeoff[(b << 8) + t] = lo + excl;
    }
    __syncthreads();
    for (int i = la + 4 * t; i < hi; i += 4 * 1024) {
        uint4 r = *(const uint4*)(sorted + i);
        if (i >= lo && i + 4 <= hi) {
            int p0 = atomicAdd(&cur[r.x >> 17], 1); nsorted[lo + p0] = r.x & 0x1FFFFu;
            int p1 = atomicAdd(&cur[r.y >> 17], 1); nsorted[lo + p1] = r.y & 0x1FFFFu;
            int p2 = atomicAdd(&cur[r.z >> 17], 1); nsorted[lo + p2] = r.z & 0x1FFFFu;
            int p3 = atomicAdd(&cur[r.w >> 17], 1); nsorted[lo + p3] = r.w & 0x1FFFFu;
        } else {
            if (i + 0 >= lo && i + 0 < hi) { int p0 = atomicAdd(&cur[r.x >> 17], 1); nsorted[lo + p0] = r.x & 0x1FFFFu; }
            if (i + 1 >= lo && i + 1 < hi) { int p1 = atomicAdd(&cur[r.y >> 17], 1); nsorted[lo + p1] = r.y & 0x1FFFFu; }
            if (i + 2 >= lo && i + 2 < hi) { int p2 = atomicAdd(&cur[r.z >> 17], 1); nsorted[lo + p2] = r.z & 0x1FFFFu; }
            if (i + 3 >= lo && i + 3 < hi) { int p3 = atomicAdd(&cur[r.w >> 17], 1); nsorted[lo + p3] = r.w & 0x1FFFFu; }
        }
    }
}

// ---------- Phase B: segmented sums, aligned uint4 record loads ----------

// layer 1 + fused MLP: gp[d] = dinv[d]*(relu(aggx@W1+b1)@W2)
__global__ void k_agg1(const unsigned* __restrict__ nsorted, const int* __restrict__ nodeoff,
                       const float* __restrict__ xp, const float* __restrict__ dinv,
                       const float* __restrict__ W1, const float* __restrict__ b1,
                       const float* __restrict__ W2, float* __restrict__ gp, int n) {
    int t = threadIdx.x;
    int nd = (blockIdx.x << 8) + (blockIdx.y << 6) + (t >> 2);
    int q = t & 3;
    if (nd >= n) return;
    int start = nodeoff[nd], end = nodeoff[nd + 1];
    const float2* xp2 = (const float2*)xp;
    float sx = 0.f, sy = 0.f;
    for (int p = (start & ~3) + 4 * q; p < end; p += 16) {
        uint4 r = *(const uint4*)(nsorted + p);   // aligned; pad covers overread
        if (p >= start && p + 4 <= end) {
            float2 f0 = xp2[r.x], f1 = xp2[r.y], f2 = xp2[r.z], f3 = xp2[r.w];
            sx += (f0.x + f1.x) + (f2.x + f3.x);
            sy += (f0.y + f1.y) + (f2.y + f3.y);
        } else {
            if (p + 0 >= start && p + 0 < end) { float2 f = xp2[r.x]; sx += f.x; sy += f.y; }
            if (p + 1 >= start && p + 1 < end) { float2 f = xp2[r.y]; sx += f.x; sy += f.y; }
            if (p + 2 >= start && p + 2 < end) { float2 f = xp2[r.z]; sx += f.x; sy += f.y; }
            if (p + 3 >= start && p + 3 < end) { float2 f = xp2[r.w]; sx += f.x; sy += f.y; }
        }
    }
    sx += __shfl_xor(sx, 1); sy += __shfl_xor(sy, 1);
    sx += __shfl_xor(sx, 2); sy += __shfl_xor(sy, 2);
    if (q == 0) {
        float d = dinv[nd];
        float2 xv = xp2[nd];
        float ax = d * (sx + xv.x), ay = d * (sy + xv.y);
        float g0 = 0.f, g1 = 0.f;
#pragma unroll
        for (int f = 0; f < 16; ++f) {
            float h = fmaf(ax, W1[f], fmaf(ay, W1[16 + f], b1[f]));
            h = fmaxf(h, 0.0f);
            g0 = fmaf(h, W2[2 * f + 0], g0);
            g1 = fmaf(h, W2[2 * f + 1], g1);
        }
        ((float2*)gp)[nd] = make_float2(d * g0, d * g1);
    }
}

// layer 2 + bias + log_softmax
__global__ void k_agg2(const unsigned* __restrict__ nsorted, const int* __restrict__ nodeoff,
                       const float* __restrict__ gp, const float* __restrict__ dinv,
                       const float* __restrict__ b2, float* __restrict__ out, int n) {
    int t = threadIdx.x;
    int nd = (blockIdx.x << 8) + (blockIdx.y << 6) + (t >> 2);
    int q = t & 3;
    if (nd >= n) return;
    int start = nodeoff[nd], end = nodeoff[nd + 1];
    const float2* gp2 = (const float2*)gp;
    float sx = 0.f, sy = 0.f;
    for (int p = (start & ~3) + 4 * q; p < end; p += 16) {
        uint4 r = *(const uint4*)(nsorted + p);
        if (p >= start && p + 4 <= end) {
            float2 f0 = gp2[r.x], f1 = gp2[r.y], f2 = gp2[r.z], f3 = gp2[r.w];
            sx += (f0.x + f1.x) + (f2.x + f3.x);
            sy += (f0.y + f1.y) + (f2.y + f3.y);
        } else {
            if (p + 0 >= start && p + 0 < end) { float2 f = gp2[r.x]; sx += f.x; sy += f.y; }
            if (p + 1 >= start && p + 1 < end) { float2 f = gp2[r.y]; sx += f.x; sy += f.y; }
            if (p + 2 >= start && p + 2 < end) { float2 f = gp2[r.z]; sx += f.x; sy += f.y; }
            if (p + 3 >= start && p + 3 < end) { float2 f = gp2[r.w]; sx += f.x; sy += f.y; }
        }
    }
    sx += __shfl_xor(sx, 1); sy += __shfl_xor(sy, 1);
    sx += __shfl_xor(sx, 2); sy += __shfl_xor(sy, 2);
    if (q == 0) {
        float d = dinv[nd];
        float2 gv = gp2[nd];
        float z0 = d * (sx + gv.x) + b2[0];
        float z1 = d * (sy + gv.y) + b2[1];
        float m = fmaxf(z0, z1);
        float lse = m + logf(expf(z0 - m) + expf(z1 - m));
        ((float2*)out)[nd] = make_float2(z0 - lse, z1 - lse);
    }
}

extern "C" void kernel_launch(void* const* d_in, const int* in_sizes, int n_in,
                              void* d_out, int out_size, void* d_ws, size_t ws_size,
                              hipStream_t stream) {
    const float* x  = (const float*)d_in[0];   // [n,2]
    const int*   ei = (const int*)d_in[1];     // [2,e]: row0=src, row1=dst
    const float* W1 = (const float*)d_in[2];   // [2,16]
    const float* b1 = (const float*)d_in[3];   // [16]
    const float* W2 = (const float*)d_in[4];   // [16,2]
    const float* b2 = (const float*)d_in[5];   // [2]
    float* out = (float*)d_out;                // [n,2]

    const int n = in_sizes[0] / 2;             // 100000
    const int e = in_sizes[1] / 2;             // 3200000
    const int* src = ei;
    const int* dst = ei + e;

    const int nbkt = (n + 255) >> 8;           // 391
    int ept = (((e + NTILE - 1) / NTILE) + 3) & ~3;   // 6252

    char* base = (char*)d_ws;
    size_t off = 0;
    auto take = [&](size_t bytes) { char* p = base + off; off += (bytes + 255) & ~(size_t)255; return p; };
    unsigned* sorted  = (unsigned*)take(((size_t)e + 8) * 4);             // 12.8 MB (+pad)
    int*      table   = (int*)take((size_t)NTILE * nbkt * 4);             // 0.8 MB
    int*      tot     = (int*)take((size_t)MAXB * 4);
    int*      bkt_off = (int*)take((size_t)(MAXB + 1) * 4);
    unsigned* nsorted = (unsigned*)take(((size_t)e + 8) * 4);             // 12.8 MB (+pad)
    int*      nodeoff = (int*)take((size_t)(nbkt * 256 + 64) * 4);        // 0.4 MB
    float*    dinv    = (float*)take((size_t)n * 4);
    float*    xp      = (float*)take((size_t)n * 8);
    float*    gp      = (float*)take((size_t)n * 8);

    dim3 gagg(nbkt, 4);

    k_hist    <<<NTILE, BLK, 0, stream>>>(dst, table, e, ept, nbkt);
    k_scan_col<<<nbkt, NTILE, 0, stream>>>(table, tot, nbkt);
    k_scan_tot<<<1, MAXB, 0, stream>>>(tot, bkt_off, nbkt);
    k_scatter <<<NTILE, BLK, 0, stream>>>(src, dst, table, tot, bkt_off, sorted, e, ept, nbkt);
    k_bsort   <<<nbkt, 1024, 0, stream>>>(sorted, bkt_off, x, dinv, xp, nsorted, nodeoff, n);
    k_agg1    <<<gagg, BLK, 0, stream>>>(nsorted, nodeoff, xp, dinv, W1, b1, W2, gp, n);
    k_agg2    <<<gagg, BLK, 0, stream>>>(nsorted, nodeoff, gp, dinv, b2, out, n);
}